// Round 4
// baseline (326.343 us; speedup 1.0000x reference)
//
#include <hip/hip_runtime.h>
#include <hip/hip_bf16.h>
#include <cstdint>

// Problem constants
#define Bn   1024
#define Tn   128
#define En   300
#define Hn   100
#define Vn   50000
#define G4n  400   // 4*H
#define MPn  50048 // V padded to mult of 64
#define NPn  448   // 4H padded to mult of 16 (28 n-tiles)
// gate-column PERMUTATION: jp = 4*u + q  <->  j = q*100 + u  (q = gate i,f,g,o)

typedef __bf16 bf16x8 __attribute__((ext_vector_type(8)));
typedef _Float16 half8 __attribute__((ext_vector_type(8)));
typedef _Float16 half2v __attribute__((ext_vector_type(2)));
typedef float  f32x4  __attribute__((ext_vector_type(4)));

// workspace byte offsets (total 72,764,608 B; <= 94 MB known-good)
#define OFF_TABLE  0ull         // f16 [Vn][448] permuted cols   44,800,000
#define OFF_OH16   44800000ull  // f16 [Bn][Tn][Hn]              26,214,400
#define OFF_WFRAG  71014400ull  // uint4 [28*4*64] W_hh B-frags     114,688
#define OFF_WFRAGB 71129088ull  // uint4 [10*28*64] W_ih B-frags    286,720
#define OFF_LLWT   71415808ull  // f32 [300][100] llW transposed    120,000
#define OFF_LV     71535808ull  // f32 [Bn][Hn]                     409,600
#define OFF_PN     71945408ull  // f32 [Bn][Hn]                     409,600
#define OFF_NEG    72355008ull  // f32 [Bn][Hn]                     409,600

__device__ __forceinline__ float sigf(float x) { return 1.0f / (1.0f + __expf(-x)); }
__device__ __forceinline__ float tanhfast(float x) { return 1.0f - 2.0f / (__expf(2.0f * x) + 1.0f); }

// LDS-only barrier: drain lgkmcnt but leave vmcnt free-running so the table
// gather prefetch + oh16 stores stay in flight across the barrier.
#define BAR_LDS() do {                                         \
    asm volatile("s_waitcnt lgkmcnt(0)" ::: "memory");          \
    __builtin_amdgcn_s_barrier();                               \
    asm volatile("" ::: "memory");                              \
} while (0)

// VALU-pipe lane shift-down by N within each 16-lane row (0-fill past row
// end): DPP row_shl:N — lane i reads lane i+N. No lgkmcnt involvement.
#define DPP_ADD_SHL(v, N) do {                                                     \
    int _s = __builtin_amdgcn_update_dpp(0, __builtin_bit_cast(int, (v)),          \
                                         0x100 | (N), 0xF, 0xF, true);             \
    (v) += __builtin_bit_cast(float, _s);                                          \
} while (0)

// -------- K0: W_hh -> f16 B-frags; W_ih -> bf16 B-frags; llW -> transposed ---
__global__ void k_prep(const float* __restrict__ W_ih, const float* __restrict__ W_hh,
                       const float* __restrict__ llW,
                       uint4* __restrict__ wfrag, uint4* __restrict__ wfragB,
                       float* __restrict__ llwt) {
    int idx = blockIdx.x * 256 + threadIdx.x;
    if (idx < 28 * 4 * 64) {  // W_hh frag: lane holds B[n=nt*16+(l&15)][k=kc*32+(l>>4)*8+j]
        int lane = idx & 63, tk = idx >> 6;
        int nt = tk >> 2, kc = tk & 3;
        int n = nt * 16 + (lane & 15);
        int k0 = kc * 32 + (lane >> 4) * 8;
        int q = n & 3, u = n >> 2;
        union { _Float16 h[8]; uint4 v; } pk;
#pragma unroll
        for (int j = 0; j < 8; j++) {
            int k = k0 + j;
            pk.h[j] = (_Float16)((u < Hn && k < Hn) ? W_hh[(size_t)(q * Hn + u) * Hn + k] : 0.0f);
        }
        wfrag[idx] = pk.v;
    }
    if (idx < 10 * 28 * 64) {  // W_ih frag (bf16): kc-major
        int lane = idx & 63, tk = idx >> 6;
        int kc = tk / 28, nsg = tk - kc * 28;
        int n = nsg * 16 + (lane & 15);
        int k0 = kc * 32 + (lane >> 4) * 8;
        int q = n & 3, u = n >> 2;
        union { __bf16 h[8]; uint4 v; } pk;
#pragma unroll
        for (int j = 0; j < 8; j++) {
            int k = k0 + j;
            pk.h[j] = (__bf16)((u < Hn && k < En) ? W_ih[(size_t)(q * Hn + u) * En + k] : 0.0f);
        }
        wfragB[idx] = pk.v;
    }
    if (idx < En * Hn) {  // llwt[k][h] = llW[h][k]
        int k = idx / Hn, h = idx - k * Hn;
        llwt[idx] = llW[(size_t)h * En + k];
    }
}

// -------- K1: table = emb @ W_ih^T + b (permuted cols, f16 out) --------------
__global__ __launch_bounds__(256, 2) void k_table(
    const float* __restrict__ emb, const uint4* __restrict__ wfragB,
    const float* __restrict__ b_ih, const float* __restrict__ b_hh,
    _Float16* __restrict__ table) {
    __shared__ __bf16 a_sh[64][328];   // 41,984 B (stride 328: rows offset 4 banks)
    const int tid = threadIdx.x;
    const int mt = blockIdx.x >> 1, nh = blockIdx.x & 1;

    // stage A: 64 rows x 320 cols (zeros past 300)
#pragma unroll
    for (int it = 0; it < 5; it++) {
        int x = it * 256 + tid;            // 0..1279
        int row = x / 20, seg = x - row * 20;
        int gr = mt * 64 + row;
        const float* ar = emb + (size_t)(gr < Vn ? gr : Vn - 1) * En;
        int c0 = seg * 16;
        union { __bf16 h[16]; bf16x8 v[2]; } pk;
#pragma unroll
        for (int g = 0; g < 4; g++) {
            int c = c0 + g * 4;
            if (c + 4 <= En) {
                float4 f = *(const float4*)(ar + c);
                pk.h[g * 4 + 0] = (__bf16)f.x; pk.h[g * 4 + 1] = (__bf16)f.y;
                pk.h[g * 4 + 2] = (__bf16)f.z; pk.h[g * 4 + 3] = (__bf16)f.w;
            } else {
                pk.h[g * 4 + 0] = (__bf16)0.f; pk.h[g * 4 + 1] = (__bf16)0.f;
                pk.h[g * 4 + 2] = (__bf16)0.f; pk.h[g * 4 + 3] = (__bf16)0.f;
            }
        }
        *(bf16x8*)&a_sh[row][c0] = pk.v[0];
        *(bf16x8*)&a_sh[row][c0 + 8] = pk.v[1];
    }
    __syncthreads();

    const int wv = tid >> 6, l = tid & 63;
    const int c16 = l & 15, quad = l >> 4;
    f32x4 acc[14];
#pragma unroll
    for (int i = 0; i < 14; i++) acc[i] = (f32x4){0.f, 0.f, 0.f, 0.f};

    uint4 bcur[14];
#pragma unroll
    for (int ns = 0; ns < 14; ns++) bcur[ns] = wfragB[((0 * 28 + nh * 14 + ns) << 6) + l];

    for (int kc = 0; kc < 10; kc++) {
        uint4 bnxt[14];
        if (kc < 9) {
#pragma unroll
            for (int ns = 0; ns < 14; ns++) bnxt[ns] = wfragB[(((kc + 1) * 28 + nh * 14 + ns) << 6) + l];
        }
        bf16x8 af = *(const bf16x8*)&a_sh[wv * 16 + c16][kc * 32 + quad * 8];
#pragma unroll
        for (int ns = 0; ns < 14; ns++)
            acc[ns] = __builtin_amdgcn_mfma_f32_16x16x32_bf16(af, __builtin_bit_cast(bf16x8, bcur[ns]), acc[ns], 0, 0, 0);
        if (kc < 9) {
#pragma unroll
            for (int ns = 0; ns < 14; ns++) bcur[ns] = bnxt[ns];
        }
    }
    // epilogue: C/D row = quad*4+r, col = c16
#pragma unroll
    for (int ns = 0; ns < 14; ns++) {
        int n = (nh * 14 + ns) * 16 + c16;
        int q = n & 3, u = n >> 2;
        if (u < Hn) {
            int j = q * Hn + u;
            float bias = b_ih[j] + b_hh[j];
#pragma unroll
            for (int r = 0; r < 4; r++) {
                int m = mt * 64 + wv * 16 + quad * 4 + r;
                if (m < Vn) table[(size_t)m * NPn + n] = (_Float16)(acc[ns][r] + bias);
            }
        }
    }
}

// -------- K2: label_vec = emb[lid] @ ll_W^T + ll_b (2-way K split) -----------
__global__ void k_label(const int* __restrict__ lwid, const float* __restrict__ emb,
                        const float* __restrict__ llwt, const float* __restrict__ llb,
                        float* __restrict__ lv) {
    __shared__ float er[En];
    __shared__ float part[Hn];
    int b = blockIdx.x;
    int lid = lwid[b];
    for (int k = threadIdx.x; k < En; k += 256) er[k] = emb[(size_t)lid * En + k];
    __syncthreads();
    int h = threadIdx.x & 127, half = threadIdx.x >> 7;
    float acc = 0.f;
    if (h < Hn) {
        int k0 = half * 150, k1 = k0 + 150;
        for (int k = k0; k < k1; k++) acc += er[k] * llwt[k * Hn + h];
        if (half == 1) part[h] = acc;
    }
    __syncthreads();
    if (h < Hn && half == 0) lv[(size_t)b * Hn + h] = acc + part[h] + llb[h];
}

// -------- K3: fused LSTM, 4 batch/block, 256 blocks = 1 block/CU -------------
// STRUCTURAL REWRITE (issue-contention fix). Evidence: VALUBusy 46% +
// MfmaUtil 35% = 81% SIMD issue-port occupancy with 2 blocks/CU sharing each
// SIMD -> per-step time was issue-bound, not latency-bound (why R0-R2 latency
// shaves were all neutral).
//  * 4 batches per block: MFMA A-row r content = h[batch r&3] (af read with
//    (c16&3)) so C row r = gates[batch r&3]: EVERY quad holds all 4 batches'
//    gates in regs 0..3, and the same 28 MFMA/wave/step serve 4 batches.
//  * grid = 256 = #CUs; LDS padded >80KB to force 1 block/CU = 1 wave/SIMD:
//    issue port exclusively owned, L drops toward the dependency chain.
//  * each lane handles 2 (u, batch) items: (u, sub) and (u, sub+2).
__global__ __launch_bounds__(256, 1) void k_lstm(
    const int* __restrict__ word_id, const int* __restrict__ sen_len,
    const _Float16* __restrict__ table, const uint4* __restrict__ wfrag,
    const float* __restrict__ lv, const float* __restrict__ linW,
    const float* __restrict__ linb, _Float16* __restrict__ oh16,
    float* __restrict__ per_neg, float* __restrict__ d_out) {
    __shared__ float    gbufs[4][560];     // per wave [4 mb][140] stride-5
    __shared__ _Float16 h_cur[2][4][144];  // [parity][mb][144] (stride 144: 2-way banks)
    __shared__ float    spw[4][16][132];   // [mb][partial j][t]
    __shared__ int      widc[4][Tn];
    __shared__ float    pos_sh[4][Hn];
    __shared__ float    lasth_sh[4][Hn];
    __shared__ float    tk_val[4][4];
    __shared__ int      tk_idx[4][4];
    __shared__ float    pad_force[9216];   // 36,864 B: total LDS ~87 KB > 80 KB
                                           // -> hard cap 1 block/CU

    const int tid = threadIdx.x;
    const int w = tid >> 6, l = tid & 63;
    const int c16 = l & 15, quad = l >> 4;
    const int b0 = blockIdx.x * 4;

    // opaque guard so pad_force is never DCE'd (sen_len in [K, T+1])
    if (__builtin_expect(sen_len[0] == -2147483647, 0)) pad_force[tid] = 1.f;

    // init: zero both h parities (incl padding cols), stage word ids
    for (int i = tid; i < 576; i += 256) ((uint32_t*)h_cur)[i] = 0u;
    for (int i = tid; i < 512; i += 256)
        widc[i >> 7][i & 127] = word_id[(b0 + (i >> 7)) * Tn + (i & 127)];

    // persistent W_hh B-fragments (live in unified VGPR/AGPR file)
    half8 bfr[7][4];
#pragma unroll
    for (int n7 = 0; n7 < 7; n7++)
#pragma unroll
        for (int kc = 0; kc < 4; kc++)
            bfr[n7][kc] = __builtin_bit_cast(half8, wfrag[((w * 7 + n7) * 4 + kc) * 64 + l]);

    // lane work identity: 2 items per lane
    const int u_loc = l >> 1, sub = l & 1;
    const int u = w * 28 + u_loc;
    const bool act = (l < 56) && (u < Hn);
    const int slen_a = act ? sen_len[b0 + sub] : 0;
    const int slen_b = act ? sen_len[b0 + sub + 2] : 0;
    const float lt_a = act ? lv[(size_t)(b0 + sub) * Hn + u] : 0.f;
    const float lt_b = act ? lv[(size_t)(b0 + sub + 2) * Hn + u] : 0.f;
    float* gb = &gbufs[w][0];

    __syncthreads();

    uint2 xa0 = {0, 0}, xa1 = {0, 0}, xb0 = {0, 0}, xb1 = {0, 0};
    if (act) {
        xa0 = *(const uint2*)(table + (size_t)widc[sub][0] * NPn + u * 4);
        xa1 = *(const uint2*)(table + (size_t)widc[sub][1] * NPn + u * 4);
        xb0 = *(const uint2*)(table + (size_t)widc[sub + 2][0] * NPn + u * 4);
        xb1 = *(const uint2*)(table + (size_t)widc[sub + 2][1] * NPn + u * 4);
    }

    float ca = 0.f, cb = 0.f, sum_a = 0.f, sum_b = 0.f, last_a = 0.f, last_b = 0.f;
    float pca = 0.f, pcb = 0.f;            // score partials of step t-1
    _Float16* oha = oh16 + (size_t)(b0 + sub) * Tn * Hn;
    _Float16* ohb = oh16 + (size_t)(b0 + sub + 2) * Tn * Hn;

    for (int t = 0; t < Tn; t++) {
        // ---- MFMA: gates[4 batches] = h . W_hh^T (A rows replicate mod 4)
        const _Float16* hp = &h_cur[t & 1][0][0];
        f32x4 acc[7];
#pragma unroll
        for (int n7 = 0; n7 < 7; n7++) acc[n7] = (f32x4){0.f, 0.f, 0.f, 0.f};
#pragma unroll
        for (int kc = 0; kc < 4; kc++) {
            half8 af = *(const half8*)(hp + (c16 & 3) * 144 + kc * 32 + quad * 8);
#pragma unroll
            for (int n7 = 0; n7 < 7; n7++)
                acc[n7] = __builtin_amdgcn_mfma_f32_16x16x32_f16(af, bfr[n7][kc], acc[n7], 0, 0, 0);
        }
        // ---- deferred score reduce for step t-1 (VALU DPP; overlaps MFMA)
        {
            float pra = pca, prb = pcb;
            DPP_ADD_SHL(pra, 2); DPP_ADD_SHL(pra, 4); DPP_ADD_SHL(pra, 8);
            DPP_ADD_SHL(prb, 2); DPP_ADD_SHL(prb, 4); DPP_ADD_SHL(prb, 8);
            if ((l & 15) < 2 && t > 0) {
                spw[l & 1][w * 4 + quad][t - 1] = pra;
                spw[2 + (l & 1)][w * 4 + quad][t - 1] = prb;
            }
        }
        // ---- gate stage: quad0 lanes hold batches 0..3 in regs 0..3
        if (l < 16) {
#pragma unroll
            for (int n7 = 0; n7 < 7; n7++) {
                int nl = n7 * 16 + l;
                int adr = (nl >> 2) * 5 + (nl & 3);
                gb[adr]       = acc[n7][0];
                gb[140 + adr] = acc[n7][1];
                gb[280 + adr] = acc[n7][2];
                gb[420 + adr] = acc[n7][3];
            }
        }
        // wave-synchronous: lgkmcnt ordering within wave, no barrier
        if (act) {
            int base = sub * 140 + u_loc * 5;
            // ---- item a (batch b0+sub)
            half2v a01 = __builtin_bit_cast(half2v, xa0.x);
            half2v a23 = __builtin_bit_cast(half2v, xa0.y);
            float gia = gb[base] + (float)a01.x;
            float gfa = gb[base + 1] + (float)a01.y;
            float gga = gb[base + 2] + (float)a23.x;
            float goa = gb[base + 3] + (float)a23.y;
            ca = sigf(gfa) * ca + sigf(gia) * tanhfast(gga);
            float ha = sigf(goa) * tanhfast(ca);
            h_cur[(t + 1) & 1][sub][u] = (_Float16)ha;
            oha[t * Hn + u] = (_Float16)ha;
            if (t < slen_a) sum_a += ha;
            if (t == slen_a - 1) last_a = ha;
            // ---- item b (batch b0+sub+2)
            int baseb = base + 280;
            half2v b01 = __builtin_bit_cast(half2v, xb0.x);
            half2v b23 = __builtin_bit_cast(half2v, xb0.y);
            float gib = gb[baseb] + (float)b01.x;
            float gfb = gb[baseb + 1] + (float)b01.y;
            float ggb = gb[baseb + 2] + (float)b23.x;
            float gob = gb[baseb + 3] + (float)b23.y;
            cb = sigf(gfb) * cb + sigf(gib) * tanhfast(ggb);
            float hb = sigf(gob) * tanhfast(cb);
            h_cur[(t + 1) & 1][sub + 2][u] = (_Float16)hb;
            ohb[t * Hn + u] = (_Float16)hb;
            if (t < slen_b) sum_b += hb;
            if (t == slen_b - 1) last_b = hb;
            pca = ha * lt_a;
            pcb = hb * lt_b;
            // ---- 2-deep table prefetch
            int tn2 = (t + 2 < Tn) ? t + 2 : Tn - 1;
            xa0 = xa1;
            xa1 = *(const uint2*)(table + (size_t)widc[sub][tn2] * NPn + u * 4);
            xb0 = xb1;
            xb1 = *(const uint2*)(table + (size_t)widc[sub + 2][tn2] * NPn + u * 4);
        } else {
            pca = 0.f; pcb = 0.f;
        }
        BAR_LDS();  // h(t+1) + spw visible to all waves; vmcnt stays in flight
    }
    // final deferred reduce for t = Tn-1
    {
        float pra = pca, prb = pcb;
        DPP_ADD_SHL(pra, 2); DPP_ADD_SHL(pra, 4); DPP_ADD_SHL(pra, 8);
        DPP_ADD_SHL(prb, 2); DPP_ADD_SHL(prb, 4); DPP_ADD_SHL(prb, 8);
        if ((l & 15) < 2) {
            spw[l & 1][w * 4 + quad][Tn - 1] = pra;
            spw[2 + (l & 1)][w * 4 + quad][Tn - 1] = prb;
        }
    }
    __syncthreads();  // spw complete; drains vmcnt (oh16 stores) before re-read
    // ---- top-4: wave w -> batch b0+w; tie-break smaller index
    {
        int sl = sen_len[b0 + w];
        float s0 = 0.f, s1 = 0.f;
#pragma unroll
        for (int j = 0; j < 16; j++) {
            s0 += spw[w][j][l];
            s1 += spw[w][j][l + 64];
        }
        if (l >= sl) s0 = -1e30f;
        if (l + 64 >= sl) s1 = -1e30f;
        bool tk0 = false, tk1 = false;
#pragma unroll
        for (int p4 = 0; p4 < 4; p4++) {
            float v = tk0 ? -1e30f : s0;
            int ix = l;
            float v1 = tk1 ? -1e30f : s1;
            if (v1 > v) { v = v1; ix = l + 64; }
            for (int off = 32; off; off >>= 1) {
                float ov = __shfl_down(v, off, 64);
                int oi = __shfl_down(ix, off, 64);
                if (ov > v || (ov == v && oi < ix)) { v = ov; ix = oi; }
            }
            v = __shfl(v, 0, 64);
            ix = __shfl(ix, 0, 64);
            if (l == 0) { tk_val[w][p4] = v; tk_idx[w][p4] = ix; }
            if (ix == l) tk0 = true;
            if (ix == l + 64) tk1 = true;
        }
    }
    __syncthreads();
    // ---- pos / per_neg / lasth (2 items per lane)
    if (act) {
        float pos_a = 0.f, ns_a = sum_a;
        float pos_b = 0.f, ns_b = sum_b;
#pragma unroll
        for (int p4 = 0; p4 < 4; p4++) {
            int ixa = tk_idx[sub][p4];
            float ra = (float)oha[ixa * Hn + u];
            pos_a += tk_val[sub][p4] * ra;
            ns_a -= ra;
            int ixb = tk_idx[sub + 2][p4];
            float rb = (float)ohb[ixb * Hn + u];
            pos_b += tk_val[sub + 2][p4] * rb;
            ns_b -= rb;
        }
        pos_sh[sub][u] = pos_a;
        lasth_sh[sub][u] = last_a;
        per_neg[(size_t)(b0 + sub) * Hn + u] = ns_a;
        pos_sh[sub + 2][u] = pos_b;
        lasth_sh[sub + 2][u] = last_b;
        per_neg[(size_t)(b0 + sub + 2) * Hn + u] = ns_b;
    }
    __syncthreads();
    // ---- projections: out_f = lin(lasth), l_rep = lin(pos), 4 batches
    if (tid < 48) {
        int which = tid / 24, r = tid - which * 24;
        int pmb = r / 6, o = r - pmb * 6;
        const float* src = which ? &pos_sh[pmb][0] : &lasth_sh[pmb][0];
        float acc2 = linb[o];
        for (int uu = 0; uu < Hn; uu++) acc2 += src[uu] * linW[o * Hn + uu];
        d_out[(which ? (Bn * 6) : 0) + (b0 + pmb) * 6 + o] = acc2;
    }
}

// -------- K4: batch cumsum of per_neg (wave-shuffle scan, 2 barriers) --------
__global__ __launch_bounds__(1024) void k_scan(const float* __restrict__ pn, float* __restrict__ neg) {
    __shared__ float wsum[16];
    __shared__ float wpre[16];
    int u = blockIdx.x, t = threadIdx.x;
    int lane = t & 63, wv = t >> 6;
    float v = pn[(size_t)t * Hn + u];
#pragma unroll
    for (int off = 1; off < 64; off <<= 1) {
        float o = __shfl_up(v, off, 64);
        if (lane >= off) v += o;
    }
    if (lane == 63) wsum[wv] = v;
    __syncthreads();
    if (t < 16) {
        float s = wsum[t];
#pragma unroll
        for (int off = 1; off < 16; off <<= 1) {
            float o = __shfl_up(s, off, 64);
            if (t >= off) s += o;
        }
        wpre[t] = s;
    }
    __syncthreads();
    float pre = wv ? wpre[wv - 1] : 0.f;
    neg[(size_t)t * Hn + u] = v + pre;
}

// -------- K5: r_rep = neg @ lin_W^T + lin_b ----------------------------------
__global__ void k_rrep(const float* __restrict__ neg, const float* __restrict__ linW,
                       const float* __restrict__ linb, float* __restrict__ d_out) {
    int gid = blockIdx.x * 256 + threadIdx.x;
    if (gid < Bn * 6) {
        int b = gid / 6, o = gid - b * 6;
        float acc = linb[o];
        for (int u = 0; u < Hn; u++) acc += neg[(size_t)b * Hn + u] * linW[o * Hn + u];
        d_out[2 * Bn * 6 + gid] = acc;
    }
}

extern "C" void kernel_launch(void* const* d_in, const int* in_sizes, int n_in,
                              void* d_out, int out_size, void* d_ws, size_t ws_size,
                              hipStream_t stream) {
    const int*   word_id = (const int*)d_in[0];
    const int*   sen_len = (const int*)d_in[1];
    const int*   lwid    = (const int*)d_in[2];
    const float* emb     = (const float*)d_in[3];
    const float* W_ih    = (const float*)d_in[4];
    const float* W_hh    = (const float*)d_in[5];
    const float* b_ih    = (const float*)d_in[6];
    const float* b_hh    = (const float*)d_in[7];
    const float* linW    = (const float*)d_in[8];
    const float* linb    = (const float*)d_in[9];
    const float* llW     = (const float*)d_in[10];
    const float* llb     = (const float*)d_in[11];

    char* ws = (char*)d_ws;
    _Float16* table  = (_Float16*)(ws + OFF_TABLE);
    _Float16* oh16   = (_Float16*)(ws + OFF_OH16);
    uint4*    wfrag  = (uint4*)(ws + OFF_WFRAG);
    uint4*    wfragB = (uint4*)(ws + OFF_WFRAGB);
    float*    llwt   = (float*)(ws + OFF_LLWT);
    float*    lvp    = (float*)(ws + OFF_LV);
    float*    pn     = (float*)(ws + OFF_PN);
    float*    neg    = (float*)(ws + OFF_NEG);
    float*    outp   = (float*)d_out;

    k_prep<<<118, 256, 0, stream>>>(W_ih, W_hh, llW, wfrag, wfragB, llwt);
    k_table<<<(MPn / 64) * 2, 256, 0, stream>>>(emb, wfragB, b_ih, b_hh, table);
    k_label<<<Bn, 256, 0, stream>>>(lwid, emb, llwt, llb, lvp);
    k_lstm<<<Bn / 4, 256, 0, stream>>>(word_id, sen_len, table, wfrag, lvp, linW, linb, oh16, pn, outp);
    k_scan<<<Hn, 1024, 0, stream>>>(pn, neg);
    k_rrep<<<(Bn * 6 + 255) / 256, 256, 0, stream>>>(neg, linW, linb, outp);
}

// Round 5
// 278.784 us; speedup vs baseline: 1.1706x; 1.1706x over previous
//
#include <hip/hip_runtime.h>
#include <hip/hip_bf16.h>
#include <cstdint>

// Problem constants
#define Bn   1024
#define Tn   128
#define En   300
#define Hn   100
#define Vn   50000
#define G4n  400   // 4*H
#define MPn  50048 // V padded to mult of 64
#define NPn  448   // 4H padded to mult of 16 (28 n-tiles)
// gate-column PERMUTATION: jp = 4*u + q  <->  j = q*100 + u  (q = gate i,f,g,o)

typedef __bf16 bf16x8 __attribute__((ext_vector_type(8)));
typedef _Float16 half8 __attribute__((ext_vector_type(8)));
typedef _Float16 half2v __attribute__((ext_vector_type(2)));
typedef float  f32x4  __attribute__((ext_vector_type(4)));

// workspace byte offsets
#define OFF_TABLE  0ull         // f16 [Vn][448] permuted cols   44,800,000
#define OFF_WFRAG  44800000ull  // uint4 [28*4*64] W_hh B-frags     114,688
#define OFF_WFRAGB 44914688ull  // uint4 [10*28*64] W_ih B-frags    286,720
#define OFF_LLWT   45201408ull  // f32 [300][100] llW transposed    120,000
#define OFF_LV     45321408ull  // f32 [Bn][Hn]                     409,600
#define OFF_PN6    45731008ull  // f32 [Bn][6]                       24,576

// fast sigmoid/tanh: v_rcp_f32 (1 instr) instead of IEEE divide (~9 instr).
__device__ __forceinline__ float sigf(float x) {
    return __builtin_amdgcn_rcpf(1.0f + __expf(-x));
}
__device__ __forceinline__ float tanhfast(float x) {
    return 1.0f - 2.0f * __builtin_amdgcn_rcpf(__expf(2.0f * x) + 1.0f);
}

// LDS-only barrier: drain lgkmcnt but leave vmcnt free-running so the table
// gather prefetch stays in flight across the barrier.
#define BAR_LDS() do {                                         \
    asm volatile("s_waitcnt lgkmcnt(0)" ::: "memory");          \
    __builtin_amdgcn_s_barrier();                               \
    asm volatile("" ::: "memory");                              \
} while (0)

// VALU-pipe lane shift-down by N within each 16-lane row (0-fill past row end)
#define DPP_ADD_SHL(v, N) do {                                                     \
    int _s = __builtin_amdgcn_update_dpp(0, __builtin_bit_cast(int, (v)),          \
                                         0x100 | (N), 0xF, 0xF, true);             \
    (v) += __builtin_bit_cast(float, _s);                                          \
} while (0)

// -------- K0: W_hh -> f16 B-frags; W_ih -> bf16 B-frags; llW -> transposed ---
__global__ void k_prep(const float* __restrict__ W_ih, const float* __restrict__ W_hh,
                       const float* __restrict__ llW,
                       uint4* __restrict__ wfrag, uint4* __restrict__ wfragB,
                       float* __restrict__ llwt) {
    int idx = blockIdx.x * 256 + threadIdx.x;
    if (idx < 28 * 4 * 64) {  // W_hh frag: lane holds B[n=nt*16+(l&15)][k=kc*32+(l>>4)*8+j]
        int lane = idx & 63, tk = idx >> 6;
        int nt = tk >> 2, kc = tk & 3;
        int n = nt * 16 + (lane & 15);
        int k0 = kc * 32 + (lane >> 4) * 8;
        int q = n & 3, u = n >> 2;
        union { _Float16 h[8]; uint4 v; } pk;
#pragma unroll
        for (int j = 0; j < 8; j++) {
            int k = k0 + j;
            pk.h[j] = (_Float16)((u < Hn && k < Hn) ? W_hh[(size_t)(q * Hn + u) * Hn + k] : 0.0f);
        }
        wfrag[idx] = pk.v;
    }
    if (idx < 10 * 28 * 64) {  // W_ih frag (bf16): kc-major
        int lane = idx & 63, tk = idx >> 6;
        int kc = tk / 28, nsg = tk - kc * 28;
        int n = nsg * 16 + (lane & 15);
        int k0 = kc * 32 + (lane >> 4) * 8;
        int q = n & 3, u = n >> 2;
        union { __bf16 h[8]; uint4 v; } pk;
#pragma unroll
        for (int j = 0; j < 8; j++) {
            int k = k0 + j;
            pk.h[j] = (__bf16)((u < Hn && k < En) ? W_ih[(size_t)(q * Hn + u) * En + k] : 0.0f);
        }
        wfragB[idx] = pk.v;
    }
    if (idx < En * Hn) {  // llwt[k][h] = llW[h][k]
        int k = idx / Hn, h = idx - k * Hn;
        llwt[idx] = llW[(size_t)h * En + k];
    }
}

// -------- K1: table = emb @ W_ih^T + b (permuted cols, f16 out) --------------
__global__ __launch_bounds__(256, 2) void k_table(
    const float* __restrict__ emb, const uint4* __restrict__ wfragB,
    const float* __restrict__ b_ih, const float* __restrict__ b_hh,
    _Float16* __restrict__ table) {
    __shared__ __bf16 a_sh[64][328];   // 41,984 B (stride 328: rows offset 4 banks)
    const int tid = threadIdx.x;
    const int mt = blockIdx.x >> 1, nh = blockIdx.x & 1;

    // stage A: 64 rows x 320 cols (zeros past 300)
#pragma unroll
    for (int it = 0; it < 5; it++) {
        int x = it * 256 + tid;            // 0..1279
        int row = x / 20, seg = x - row * 20;
        int gr = mt * 64 + row;
        const float* ar = emb + (size_t)(gr < Vn ? gr : Vn - 1) * En;
        int c0 = seg * 16;
        union { __bf16 h[16]; bf16x8 v[2]; } pk;
#pragma unroll
        for (int g = 0; g < 4; g++) {
            int c = c0 + g * 4;
            if (c + 4 <= En) {
                float4 f = *(const float4*)(ar + c);
                pk.h[g * 4 + 0] = (__bf16)f.x; pk.h[g * 4 + 1] = (__bf16)f.y;
                pk.h[g * 4 + 2] = (__bf16)f.z; pk.h[g * 4 + 3] = (__bf16)f.w;
            } else {
                pk.h[g * 4 + 0] = (__bf16)0.f; pk.h[g * 4 + 1] = (__bf16)0.f;
                pk.h[g * 4 + 2] = (__bf16)0.f; pk.h[g * 4 + 3] = (__bf16)0.f;
            }
        }
        *(bf16x8*)&a_sh[row][c0] = pk.v[0];
        *(bf16x8*)&a_sh[row][c0 + 8] = pk.v[1];
    }
    __syncthreads();

    const int wv = tid >> 6, l = tid & 63;
    const int c16 = l & 15, quad = l >> 4;
    f32x4 acc[14];
#pragma unroll
    for (int i = 0; i < 14; i++) acc[i] = (f32x4){0.f, 0.f, 0.f, 0.f};

    uint4 bcur[14];
#pragma unroll
    for (int ns = 0; ns < 14; ns++) bcur[ns] = wfragB[((0 * 28 + nh * 14 + ns) << 6) + l];

    for (int kc = 0; kc < 10; kc++) {
        uint4 bnxt[14];
        if (kc < 9) {
#pragma unroll
            for (int ns = 0; ns < 14; ns++) bnxt[ns] = wfragB[(((kc + 1) * 28 + nh * 14 + ns) << 6) + l];
        }
        bf16x8 af = *(const bf16x8*)&a_sh[wv * 16 + c16][kc * 32 + quad * 8];
#pragma unroll
        for (int ns = 0; ns < 14; ns++)
            acc[ns] = __builtin_amdgcn_mfma_f32_16x16x32_bf16(af, __builtin_bit_cast(bf16x8, bcur[ns]), acc[ns], 0, 0, 0);
        if (kc < 9) {
#pragma unroll
            for (int ns = 0; ns < 14; ns++) bcur[ns] = bnxt[ns];
        }
    }
    // epilogue: C/D row = quad*4+r, col = c16
#pragma unroll
    for (int ns = 0; ns < 14; ns++) {
        int n = (nh * 14 + ns) * 16 + c16;
        int q = n & 3, u = n >> 2;
        if (u < Hn) {
            int j = q * Hn + u;
            float bias = b_ih[j] + b_hh[j];
#pragma unroll
            for (int r = 0; r < 4; r++) {
                int m = mt * 64 + wv * 16 + quad * 4 + r;
                if (m < Vn) table[(size_t)m * NPn + n] = (_Float16)(acc[ns][r] + bias);
            }
        }
    }
}

// -------- K2: label_vec = emb[lid] @ ll_W^T + ll_b (2-way K split) -----------
__global__ void k_label(const int* __restrict__ lwid, const float* __restrict__ emb,
                        const float* __restrict__ llwt, const float* __restrict__ llb,
                        float* __restrict__ lv) {
    __shared__ float er[En];
    __shared__ float part[Hn];
    int b = blockIdx.x;
    int lid = lwid[b];
    for (int k = threadIdx.x; k < En; k += 256) er[k] = emb[(size_t)lid * En + k];
    __syncthreads();
    int h = threadIdx.x & 127, half = threadIdx.x >> 7;
    float acc = 0.f;
    if (h < Hn) {
        int k0 = half * 150, k1 = k0 + 150;
        for (int k = k0; k < k1; k++) acc += er[k] * llwt[k * Hn + h];
        if (half == 1) part[h] = acc;
    }
    __syncthreads();
    if (h < Hn && half == 0) lv[(size_t)b * Hn + h] = acc + part[h] + llb[h];
}

// -------- K3: fused LSTM, 2 batch/block (R3 placement), issue-dieted ---------
// Evidence trail: R3 = 81% SIMD issue occupancy at 2 blocks/CU (VALU 46 +
// MFMA 35); R4 (1 blk/CU) proved removing the co-resident wave HURTS.
// This rev keeps R3 placement and cuts per-wave ISSUE count:
//  * rcpf transcendentals (-~45 VALU instr/item, -~150 cy chain)
//  * zero-C first MFMA (-28 movs/step)
//  * oh kept in LDS, not global (-store+addr/step; epilogue gathers LDS)
//  * premultiplied word-id offsets (-mul/step)
//  * per_neg projected to 6 dims in-kernel (k_rrep fused; cumsum commutes)
__global__ __launch_bounds__(256, 2) void k_lstm(
    const int* __restrict__ word_id, const int* __restrict__ sen_len,
    const _Float16* __restrict__ table, const uint4* __restrict__ wfrag,
    const float* __restrict__ lv, const float* __restrict__ linW,
    const float* __restrict__ linb, float* __restrict__ pn6,
    float* __restrict__ d_out) {
    __shared__ float    gbufs[4][280];       // per wave [2 mb][140] stride-5
    __shared__ _Float16 h_cur[2][2][136];    // [parity][mb][136], cols>=100 zero
    __shared__ _Float16 oh_lds[2][12832];    // [mb][t*100+u] + 32-elt inter-mb pad
    __shared__ float    spw[2][Tn][16];      // per-(wave,row) score partials
    __shared__ int      widc[2][Tn];         // premultiplied: wid*NPn
    __shared__ float    pos_sh[2][Hn];
    __shared__ float    lasth_sh[2][Hn];
    __shared__ float    neg_sh[2][Hn];
    __shared__ float    tk_val[2][4];
    __shared__ int      tk_idx[2][4];

    const int tid = threadIdx.x;
    const int w = tid >> 6, l = tid & 63;
    const int c16 = l & 15, quad = l >> 4;
    const int b0 = blockIdx.x * 2;

    // init
    for (int i = tid; i < 272; i += 256) ((uint32_t*)h_cur)[i] = 0u;  // both parities + pads
    { int imb = tid >> 7, it = tid & 127; widc[imb][it] = word_id[(b0 + imb) * Tn + it] * NPn; }

    // persistent W_hh B-fragments (unified VGPR/AGPR file)
    half8 bfr[7][4];
#pragma unroll
    for (int n7 = 0; n7 < 7; n7++)
#pragma unroll
        for (int kc = 0; kc < 4; kc++)
            bfr[n7][kc] = __builtin_bit_cast(half8, wfrag[((w * 7 + n7) * 4 + kc) * 64 + l]);

    // lane work identity
    const int u_loc = l >> 1, mb = l & 1;
    const int u = w * 28 + u_loc;
    const bool act = (l < 56) && (u < Hn);
    const int myslen = act ? sen_len[b0 + mb] : 0;
    const float lt_reg = act ? lv[(size_t)(b0 + mb) * Hn + u] : 0.f;
    float* gb = &gbufs[w][0];
    const _Float16* tb_u = table + u * 4;    // per-lane column base

    __syncthreads();

    uint2 xq = {0, 0}, xq1 = {0, 0};
    if (act) {
        xq  = *(const uint2*)(tb_u + (size_t)widc[mb][0]);
        xq1 = *(const uint2*)(tb_u + (size_t)widc[mb][1]);
    }

    float c_reg = 0.f, sumh = 0.f, lasth = 0.f;
    float p_carry = 0.f;                    // score partial of step t-1

    for (int t = 0; t < Tn; t++) {
        // ---- MFMA: gates = h . W_hh^T (A from parity t&1); kc=0 takes C=0
        const _Float16* hp = &h_cur[t & 1][0][0];
        f32x4 acc[7];
        {
            half8 af0 = *(const half8*)(hp + (c16 & 1) * 136 + quad * 8);
#pragma unroll
            for (int n7 = 0; n7 < 7; n7++)
                acc[n7] = __builtin_amdgcn_mfma_f32_16x16x32_f16(
                    af0, bfr[n7][0], (f32x4){0.f, 0.f, 0.f, 0.f}, 0, 0, 0);
        }
#pragma unroll
        for (int kc = 1; kc < 4; kc++) {
            half8 af = *(const half8*)(hp + (c16 & 1) * 136 + kc * 32 + quad * 8);
#pragma unroll
            for (int n7 = 0; n7 < 7; n7++)
                acc[n7] = __builtin_amdgcn_mfma_f32_16x16x32_f16(af, bfr[n7][kc], acc[n7], 0, 0, 0);
        }
        // ---- wave-local gate stage FIRST (start the LDS round trip early)
        if (l < 16) {
#pragma unroll
            for (int n7 = 0; n7 < 7; n7++) {
                int nl = n7 * 16 + l;
                int adr = (nl >> 2) * 5 + (nl & 3);
                gb[adr] = acc[n7][0];
                gb[140 + adr] = acc[n7][1];
            }
        }
        // ---- deferred score reduce for step t-1 (VALU DPP; hides gb wait)
        {
            float pr = p_carry;
            DPP_ADD_SHL(pr, 2);
            DPP_ADD_SHL(pr, 4);
            DPP_ADD_SHL(pr, 8);
            if ((l & 15) < 2 && t > 0) spw[l & 1][t - 1][w * 4 + quad] = pr;
        }
        // wave-synchronous: lgkmcnt ordering within wave, no barrier
        float p = 0.f;
        if (act) {
            int base = mb * 140 + u_loc * 5;
            half2v x01 = __builtin_bit_cast(half2v, xq.x);
            half2v x23 = __builtin_bit_cast(half2v, xq.y);
            float gi = gb[base] + (float)x01.x;
            float gf = gb[base + 1] + (float)x01.y;
            float gg = gb[base + 2] + (float)x23.x;
            float go = gb[base + 3] + (float)x23.y;
            float c = sigf(gf) * c_reg + sigf(gi) * tanhfast(gg);
            c_reg = c;
            float hh = sigf(go) * tanhfast(c);
            _Float16 h16 = (_Float16)hh;
            h_cur[(t + 1) & 1][mb][u] = h16;
            oh_lds[mb][t * Hn + u] = h16;
            if (t < myslen) sumh += hh;
            if (t == myslen - 1) lasth = hh;
            p = hh * lt_reg;
            int tn2 = (t + 2 < Tn) ? t + 2 : Tn - 1;
            xq = xq1;
            xq1 = *(const uint2*)(tb_u + (size_t)widc[mb][tn2]);
        }
        p_carry = p;
        BAR_LDS();  // h(t+1) + spw visible to all waves; vmcnt stays in flight
    }
    // final deferred reduce for t = Tn-1
    {
        float pr = p_carry;
        DPP_ADD_SHL(pr, 2);
        DPP_ADD_SHL(pr, 4);
        DPP_ADD_SHL(pr, 8);
        if ((l & 15) < 2) spw[l & 1][Tn - 1][w * 4 + quad] = pr;
    }
    __syncthreads();
    // ---- top-4: wave 0 -> mb 0, wave 1 -> mb 1; tie-break smaller index
    if (w < 2) {
        int kmb = w, lane = l;
        int sl = sen_len[b0 + kmb];
        const float* s16a = &spw[kmb][lane][0];
        const float* s16b = &spw[kmb][lane + 64][0];
        float4 a0 = *(const float4*)(s16a + 0), a1 = *(const float4*)(s16a + 4);
        float4 a2 = *(const float4*)(s16a + 8), a3 = *(const float4*)(s16a + 12);
        float4 b0v = *(const float4*)(s16b + 0), b1v = *(const float4*)(s16b + 4);
        float4 b2v = *(const float4*)(s16b + 8), b3v = *(const float4*)(s16b + 12);
        float sa = (a0.x + a0.y + a0.z + a0.w) + (a1.x + a1.y + a1.z + a1.w)
                 + (a2.x + a2.y + a2.z + a2.w) + (a3.x + a3.y + a3.z + a3.w);
        float sb = (b0v.x + b0v.y + b0v.z + b0v.w) + (b1v.x + b1v.y + b1v.z + b1v.w)
                 + (b2v.x + b2v.y + b2v.z + b2v.w) + (b3v.x + b3v.y + b3v.z + b3v.w);
        float s0 = (lane < sl) ? sa : -1e30f;
        float s1 = (lane + 64 < sl) ? sb : -1e30f;
        bool tk0 = false, tk1 = false;
#pragma unroll
        for (int p4 = 0; p4 < 4; p4++) {
            float v = tk0 ? -1e30f : s0;
            int ix = lane;
            float v1 = tk1 ? -1e30f : s1;
            if (v1 > v) { v = v1; ix = lane + 64; }
            for (int off = 32; off; off >>= 1) {
                float ov = __shfl_down(v, off, 64);
                int oi = __shfl_down(ix, off, 64);
                if (ov > v || (ov == v && oi < ix)) { v = ov; ix = oi; }
            }
            v = __shfl(v, 0, 64);
            ix = __shfl(ix, 0, 64);
            if (lane == 0) { tk_val[kmb][p4] = v; tk_idx[kmb][p4] = ix; }
            if (ix == lane) tk0 = true;
            if (ix == lane + 64) tk1 = true;
        }
    }
    __syncthreads();
    // ---- pos / neg / lasth (lane ownership; gathers from LDS)
    if (act) {
        float pos = 0.f, nsum = sumh;
#pragma unroll
        for (int p4 = 0; p4 < 4; p4++) {
            int ix = tk_idx[mb][p4];
            float r = (float)oh_lds[mb][ix * Hn + u];
            pos += tk_val[mb][p4] * r;
            nsum -= r;
        }
        pos_sh[mb][u] = pos;
        lasth_sh[mb][u] = lasth;
        neg_sh[mb][u] = nsum;
    }
    __syncthreads();
    // ---- projections: out_f = lin(lasth), l_rep = lin(pos), pn6 = lin0(neg)
    if (tid < 36) {
        int which = tid / 12, r = tid - which * 12;
        int pmb = r / 6, o = r - pmb * 6;
        const float* src = (which == 0) ? &lasth_sh[pmb][0]
                         : (which == 1) ? &pos_sh[pmb][0] : &neg_sh[pmb][0];
        float acc2 = (which == 2) ? 0.f : linb[o];
        for (int uu = 0; uu < Hn; uu++) acc2 += src[uu] * linW[o * Hn + uu];
        if (which == 0)      d_out[(b0 + pmb) * 6 + o] = acc2;
        else if (which == 1) d_out[Bn * 6 + (b0 + pmb) * 6 + o] = acc2;
        else                 pn6[(b0 + pmb) * 6 + o] = acc2;  // bias added post-cumsum
    }
}

// -------- K4: r_rep = cumsum_b(pn6) + linb (wave-shuffle scan, writes d_out) -
__global__ __launch_bounds__(1024) void k_scan6(const float* __restrict__ pn6,
                                                const float* __restrict__ linb,
                                                float* __restrict__ d_out) {
    __shared__ float wsum[16];
    __shared__ float wpre[16];
    int o = blockIdx.x, t = threadIdx.x;
    int lane = t & 63, wv = t >> 6;
    float v = pn6[t * 6 + o];
#pragma unroll
    for (int off = 1; off < 64; off <<= 1) {
        float x = __shfl_up(v, off, 64);
        if (lane >= off) v += x;
    }
    if (lane == 63) wsum[wv] = v;
    __syncthreads();
    if (t < 16) {
        float s = wsum[t];
#pragma unroll
        for (int off = 1; off < 16; off <<= 1) {
            float x = __shfl_up(s, off, 64);
            if (t >= off) s += x;
        }
        wpre[t] = s;
    }
    __syncthreads();
    float pre = wv ? wpre[wv - 1] : 0.f;
    d_out[2 * Bn * 6 + t * 6 + o] = v + pre + linb[o];
}

extern "C" void kernel_launch(void* const* d_in, const int* in_sizes, int n_in,
                              void* d_out, int out_size, void* d_ws, size_t ws_size,
                              hipStream_t stream) {
    const int*   word_id = (const int*)d_in[0];
    const int*   sen_len = (const int*)d_in[1];
    const int*   lwid    = (const int*)d_in[2];
    const float* emb     = (const float*)d_in[3];
    const float* W_ih    = (const float*)d_in[4];
    const float* W_hh    = (const float*)d_in[5];
    const float* b_ih    = (const float*)d_in[6];
    const float* b_hh    = (const float*)d_in[7];
    const float* linW    = (const float*)d_in[8];
    const float* linb    = (const float*)d_in[9];
    const float* llW     = (const float*)d_in[10];
    const float* llb     = (const float*)d_in[11];

    char* ws = (char*)d_ws;
    _Float16* table  = (_Float16*)(ws + OFF_TABLE);
    uint4*    wfrag  = (uint4*)(ws + OFF_WFRAG);
    uint4*    wfragB = (uint4*)(ws + OFF_WFRAGB);
    float*    llwt   = (float*)(ws + OFF_LLWT);
    float*    lvp    = (float*)(ws + OFF_LV);
    float*    pn6    = (float*)(ws + OFF_PN6);
    float*    outp   = (float*)d_out;

    k_prep<<<118, 256, 0, stream>>>(W_ih, W_hh, llW, wfrag, wfragB, llwt);
    k_table<<<(MPn / 64) * 2, 256, 0, stream>>>(emb, wfragB, b_ih, b_hh, table);
    k_label<<<Bn, 256, 0, stream>>>(lwid, emb, llwt, llb, lvp);
    k_lstm<<<Bn / 2, 256, 0, stream>>>(word_id, sen_len, table, wfrag, lvp, linW, linb, pn6, outp);
    k_scan6<<<6, 1024, 0, stream>>>(pn6, linb, outp);
}